// Round 16
// baseline (327.841 us; speedup 1.0000x reference)
//
#include <hip/hip_runtime.h>
#include <hip/hip_bf16.h>

#define NN 131072
#define NE 2097152
#define FIN 32
#define HID 64
#define GFC 16
#define NG 1024
#define EPS 1e-5f
#define NBK 512      // buckets (dst>>8), 256 nodes each
#define BCAP 4800    // per-bucket bin capacity (mean 4096, +11 sigma)
#define PBCAP 5568   // padded bucket capacity: BCAP + 256*3 (pad-to-4)

typedef __hip_bfloat16 bf16;
typedef __attribute__((ext_vector_type(8))) short v8s;   // 8 bf16 = 4 VGPRs
typedef __attribute__((ext_vector_type(4))) float v4f;   // MFMA accumulator

__device__ __forceinline__ bf16 f2b(float v) { return __float2bfloat16(v); }
__device__ __forceinline__ float b2f(bf16 v) { return __bfloat162float(v); }
__device__ __forceinline__ void rG_err(int* err, int code) { atomicCAS(err, 0, code); }

// pack two f32 -> 2x bf16 in one u32
__device__ __forceinline__ unsigned rG_pk(float a, float b) {
    bf16 h0 = f2b(a), h1 = f2b(b);
    unsigned short u0 = *(unsigned short*)&h0;
    unsigned short u1 = *(unsigned short*)&h1;
    return (unsigned)u0 | ((unsigned)u1 << 16);
}

// accumulate 8 bf16 (as uint4) into acc[8]
__device__ __forceinline__ void rG_add8(float* acc, uint4 a) {
    const unsigned* u = (const unsigned*)&a;
#pragma unroll
    for (int q = 0; q < 4; q++) {
        acc[2 * q]     += __uint_as_float(u[q] << 16);
        acc[2 * q + 1] += __uint_as_float(u[q] & 0xFFFF0000u);
    }
}

// ---------- broadcast diagnostic code (f32 output) ----------
__global__ void rG_code(float code, float* out) {
    int i = blockIdx.x * blockDim.x + threadIdx.x;
    if (i < 2048) out[i] = code;
}

// ---------- bin edges into 512 coarse buckets (dst>>8) -----------------------
// + fused batch hist + per-node in-degree histogram (global atomics; feeds the
// single-pass sortxw so it never re-reads bin for counting).
__global__ __launch_bounds__(1024) void rG_bin(const int* ei, const int* batch,
                                               unsigned* bin, int* bin_cnt,
                                               int* deg, int* graph_cnt, int* err) {
    __shared__ unsigned lsort[4096];
    __shared__ unsigned short bof[4096];
    __shared__ int h[NBK];
    __shared__ int h2[NBK];
    __shared__ int lbase[NBK];
    __shared__ int gbase[NBK];
    int t = threadIdx.x;
    // fused batch histogram: 256 sorted nodes per block (waves 0-3)
    if (t < 256) {
        int lane = t & 63;
        int n = blockIdx.x * 256 + t;
        int bg = batch[n];
        if ((unsigned)bg >= NG) { rG_err(err, 3100); bg = 0; }
        int bgp = __shfl_up(bg, 1);
        bool head = (lane == 0) || (bgp != bg);
        int bgn = __shfl_down(bg, 1);
        bool last = (lane == 63) || (bgn != bg);
        unsigned long long hm = __ballot(head);
        if (last) {
            unsigned long long below =
                (lane == 63) ? hm : (hm & ((1ULL << (lane + 1)) - 1ULL));
            int start = 63 - __clzll(below);
            atomicAdd(&graph_cnt[bg], lane - start + 1);
        }
    }
    if (t < NBK) { h[t] = 0; h2[t] = 0; }
    __syncthreads();
    // 4096 edges/block = 1 int4 per thread per array
    const int4* si4 = (const int4*)ei;
    const int4* di4 = (const int4*)(ei + NE);
    int e4 = blockIdx.x * 1024 + t;
    int4 s4 = si4[e4];
    int4 d4 = di4[e4];
    int sv[4] = {s4.x, s4.y, s4.z, s4.w};
    int dv[4] = {d4.x, d4.y, d4.z, d4.w};
    unsigned vals[4];
    unsigned short bks[4];
#pragma unroll
    for (int q = 0; q < 4; q++) {
        int s = sv[q], d = dv[q];
        if ((unsigned)s >= NN || (unsigned)d >= NN) { rG_err(err, 3000); s = 0; d = 0; }
        int b = d >> 8;
        vals[q] = ((unsigned)(d & 255) << 17) | (unsigned)s;
        bks[q] = (unsigned short)b;
        atomicAdd(&h[b], 1);
        atomicAdd(&deg[d], 1);              // per-node in-degree (fire-and-forget)
    }
    __syncthreads();
    // inclusive scan of h (512 entries, first 512 threads)
    if (t < NBK) lbase[t] = h[t];
    __syncthreads();
    for (int off = 1; off < NBK; off <<= 1) {
        int v = 0;
        if (t < NBK && t >= off) v = lbase[t - off];
        __syncthreads();
        if (t < NBK) lbase[t] += v;
        __syncthreads();
    }
    if (t < NBK) {
        gbase[t] = atomicAdd(&bin_cnt[t], h[t]);
        lbase[t] -= h[t];   // exclusive
    }
    __syncthreads();
    // scatter into LDS, sorted by bucket
#pragma unroll
    for (int q = 0; q < 4; q++) {
        int b = bks[q];
        int r = atomicAdd(&h2[b], 1);
        int pos = lbase[b] + r;
        lsort[pos] = vals[q];
        bof[pos] = (unsigned short)b;
    }
    __syncthreads();
    // coalesced copy-out: consecutive i within a run -> consecutive global addrs
    for (int i = t; i < 4096; i += 1024) {
        int b = bof[i];
        int p = gbase[b] + (i - lbase[b]);
        if (p >= BCAP) { rG_err(err, 3800); continue; }
        bin[b * BCAP + p] = lsort[i];
    }
}

// ---------- per-bucket SINGLE-PASS sort (deg known from rG_bin) --------------
// scan 4-padded degrees -> bases; one pass over bin scatters into LDS; pads
// written directly. + block 0 NE validation + fused xw1 (lout reused).
__global__ __launch_bounds__(1024) void rG_sortxw(const unsigned* bin, const int* bin_cnt,
                                                  const int* deg, const float* x,
                                                  const float* W1,
                                                  int* row_ptr, float* dinv,
                                                  int* col_src, bf16* y, int* err) {
    __shared__ int cnt[256];
    __shared__ int sA[256];
    __shared__ int sB[256];
    __shared__ int bas[256];
    __shared__ float dinvl[256];
    __shared__ int lout[6272];   // 25 KB: max(PBCAP=5568, ws 2048 + xs 4224)
    int t = threadIdx.x;
    int b = blockIdx.x;
    int d = 0;
    if (t < 256) {
        d = deg[b * 256 + t];
        cnt[t] = 0;
        sA[t] = (d + 3) & ~3;
    }
    __syncthreads();
    // inclusive scan of 4-padded degrees, 256 entries
    int* src = sA;
    int* dst = sB;
    for (int off = 1; off < 256; off <<= 1) {
        if (t < 256) dst[t] = src[t] + ((t >= off) ? src[t - off] : 0);
        __syncthreads();
        int* tmp = src; src = dst; dst = tmp;
    }
    int gb = b * PBCAP;
    if (t < 256) {
        int c4 = (d + 3) & ~3;
        int basl = src[t] - c4;             // local base within bucket
        bas[t] = basl;
        row_ptr[b * 256 + t] = gb + basl;
        float dv = rsqrtf((float)d + 1.0f);
        dinv[b * 256 + t] = dv;
        dinvl[t] = dv;
    }
    __syncthreads();
    int tot = src[255];                     // total padded edges this bucket
    bool ok = (tot <= PBCAP);
    if (!ok && t == 0) rG_err(err, 3900);
    // pad slots [basl+d, basl+c4) get sentinel directly (disjoint from scatter)
    if (ok && t < 256) {
        for (int k = d; k < ((d + 3) & ~3); k++) lout[bas[t] + k] = NN;
    }
    __syncthreads();
    int m = bin_cnt[b];
    if (m > BCAP) m = BCAP;
    // single pass: scatter into LDS (bin read once, L2-hot)
    if (ok) {
        for (int j = t; j < m; j += 1024) {
            unsigned v = bin[b * BCAP + j];
            int dl = v >> 17;
            int r = atomicAdd(&cnt[dl], 1);
            lout[bas[dl] + r] = (int)(v & 0x1FFFFu);
        }
    }
    __syncthreads();
    // fully coalesced write-out
    if (ok) {
        for (int i = t; i < tot; i += 1024) col_src[gb + i] = lout[i];
    }
    __syncthreads();
    // ---- block 0: validate total edge count ----
    if (b == 0) {
        if (t < 256) sA[t] = bin_cnt[t] + bin_cnt[t + 256];
        __syncthreads();
        for (int off = 128; off > 0; off >>= 1) {
            if (t < off) sA[t] += sA[t + off];
            __syncthreads();
        }
        if (t == 0 && sA[0] != NE) rG_err(err, 2000);
    }
    // ---- fused xw1 for nodes b*256 .. +255 (lout memory now dead) ----
    float* ws = (float*)lout;               // FIN*HID = 2048 f32 (8 KB)
    float* xs = ws + FIN * HID;             // 128*(FIN+1) = 4224 f32 (16.9 KB)
    for (int i = t; i < FIN * HID; i += 1024) ws[i] = W1[i];
    if (b == 0 && t < HID) y[(size_t)NN * HID + t] = f2b(0.f);  // zero row
    for (int ch = 0; ch < 2; ch++) {
        __syncthreads();                    // xs reuse + (first iter) ws ready
        int nb0 = b * 256 + ch * 128;
        {
            // 128 nodes x 32 f32 = 1024 float4: one per thread
            float4 f4 = ((const float4*)x)[(size_t)nb0 * 8 + t];
            int nd = t >> 3, k4 = (t & 7) * 4;
            float* xp = xs + nd * (FIN + 1) + k4;
            xp[0] = f4.x; xp[1] = f4.y; xp[2] = f4.z; xp[3] = f4.w;
        }
        __syncthreads();
        int node = t >> 3, fg = t & 7;
        float acc[8];
#pragma unroll
        for (int j = 0; j < 8; j++) acc[j] = 0.f;
        for (int k = 0; k < FIN; k++) {
            float xv = xs[node * (FIN + 1) + k];
#pragma unroll
            for (int j = 0; j < 8; j++) acc[j] += xv * ws[k * HID + fg * 8 + j];
        }
        float dv = dinvl[ch * 128 + node];
        unsigned o[4];
#pragma unroll
        for (int q = 0; q < 4; q++) o[q] = rG_pk(acc[2 * q] * dv, acc[2 * q + 1] * dv);
        *(uint4*)(y + (size_t)(nb0 + node) * HID + fg * 8) = *(uint4*)o;
    }
}

// ---------- CSR aggregation: DUAL-STREAM, 16 nodes/wave, pad-to-4 rows -------
// degp computed inline from deg: eX1 = eX + ((deg+3)&~3)
__global__ __launch_bounds__(256) void rG_agg(const int* row_ptr, const int* deg,
                                              const int* col_src,
                                              const float* dinv, const float* bias,
                                              const bf16* y, bf16* outb, float* stats) {
    int t = threadIdx.x;
    int lane = t & 63, wave = t >> 6;
    int ns = lane >> 3;
    int c = lane & 7;
    float bl[8];
#pragma unroll
    for (int k = 0; k < 8; k++) bl[k] = bias[c * 8 + k];
    float ssum[8], ssq[8];
#pragma unroll
    for (int k = 0; k < 8; k++) { ssum[k] = 0.f; ssq[k] = 0.f; }
    int gw = blockIdx.x * 4 + wave;
    int nw = gridDim.x * 4;
    for (int nb = gw * 16; nb < NN; nb += nw * 16) {
        int nA = nb + ns, nB = nb + 8 + ns;
        int eA = row_ptr[nA], eA1 = eA + ((deg[nA] + 3) & ~3);
        int eB = row_ptr[nB], eB1 = eB + ((deg[nB] + 3) & ~3);
        float accA[8], accB[8];
#pragma unroll
        for (int k = 0; k < 8; k++) { accA[k] = 0.f; accB[k] = 0.f; }
        uint4 svA = *(const uint4*)(y + (size_t)nA * HID + c * 8);
        uint4 svB = *(const uint4*)(y + (size_t)nB * HID + c * 8);
        uint4 iA0 = {0, 0, 0, 0}, iA1 = iA0, iB0 = iA0, iB1 = iA0;
        if (eA < eA1) {
            iA0 = *(const uint4*)(col_src + eA);
            iA1 = *(const uint4*)(col_src + eA + 4);
        }
        if (eB < eB1) {
            iB0 = *(const uint4*)(col_src + eB);
            iB1 = *(const uint4*)(col_src + eB + 4);
        }
        rG_add8(accA, svA);
        rG_add8(accB, svB);
        while (eA + 8 <= eA1 || eB + 8 <= eB1) {
            bool pA = eA + 8 <= eA1, pB = eB + 8 <= eB1;
            uint4 fA0 = iA0, fA1 = iA1, fB0 = iB0, fB1 = iB1;
            if (pA && eA + 8 < eA1) {
                fA0 = *(const uint4*)(col_src + eA + 8);
                fA1 = *(const uint4*)(col_src + eA + 12);
            }
            if (pB && eB + 8 < eB1) {
                fB0 = *(const uint4*)(col_src + eB + 8);
                fB1 = *(const uint4*)(col_src + eB + 12);
            }
            uint4 gA[8], gB[8];
            if (pA) {
                int ix[8] = {(int)iA0.x, (int)iA0.y, (int)iA0.z, (int)iA0.w,
                             (int)iA1.x, (int)iA1.y, (int)iA1.z, (int)iA1.w};
#pragma unroll
                for (int i = 0; i < 8; i++)
                    gA[i] = *(const uint4*)(y + (size_t)ix[i] * HID + c * 8);
            }
            if (pB) {
                int ix[8] = {(int)iB0.x, (int)iB0.y, (int)iB0.z, (int)iB0.w,
                             (int)iB1.x, (int)iB1.y, (int)iB1.z, (int)iB1.w};
#pragma unroll
                for (int i = 0; i < 8; i++)
                    gB[i] = *(const uint4*)(y + (size_t)ix[i] * HID + c * 8);
            }
            if (pA) {
#pragma unroll
                for (int i = 0; i < 8; i++) rG_add8(accA, gA[i]);
                eA += 8; iA0 = fA0; iA1 = fA1;
            }
            if (pB) {
#pragma unroll
                for (int i = 0; i < 8; i++) rG_add8(accB, gB[i]);
                eB += 8; iB0 = fB0; iB1 = fB1;
            }
        }
        if (eA < eA1) {                           // 4-tail (indices in iA0)
            int ix[4] = {(int)iA0.x, (int)iA0.y, (int)iA0.z, (int)iA0.w};
            uint4 g[4];
#pragma unroll
            for (int i = 0; i < 4; i++)
                g[i] = *(const uint4*)(y + (size_t)ix[i] * HID + c * 8);
#pragma unroll
            for (int i = 0; i < 4; i++) rG_add8(accA, g[i]);
        }
        if (eB < eB1) {                           // 4-tail (indices in iB0)
            int ix[4] = {(int)iB0.x, (int)iB0.y, (int)iB0.z, (int)iB0.w};
            uint4 g[4];
#pragma unroll
            for (int i = 0; i < 4; i++)
                g[i] = *(const uint4*)(y + (size_t)ix[i] * HID + c * 8);
#pragma unroll
            for (int i = 0; i < 4; i++) rG_add8(accB, g[i]);
        }
        {
            float dv = dinv[nA];
            unsigned ob[4];
#pragma unroll
            for (int q = 0; q < 4; q++) {
                float o0 = accA[2 * q] * dv + bl[2 * q];
                float o1 = accA[2 * q + 1] * dv + bl[2 * q + 1];
                ssum[2 * q] += o0; ssq[2 * q] += o0 * o0;
                ssum[2 * q + 1] += o1; ssq[2 * q + 1] += o1 * o1;
                ob[q] = rG_pk(o0, o1);
            }
            *(uint4*)(outb + (size_t)nA * HID + c * 8) = *(uint4*)ob;
        }
        {
            float dv = dinv[nB];
            unsigned ob[4];
#pragma unroll
            for (int q = 0; q < 4; q++) {
                float o0 = accB[2 * q] * dv + bl[2 * q];
                float o1 = accB[2 * q + 1] * dv + bl[2 * q + 1];
                ssum[2 * q] += o0; ssq[2 * q] += o0 * o0;
                ssum[2 * q + 1] += o1; ssq[2 * q + 1] += o1 * o1;
                ob[q] = rG_pk(o0, o1);
            }
            *(uint4*)(outb + (size_t)nB * HID + c * 8) = *(uint4*)ob;
        }
    }
#pragma unroll
    for (int m = 8; m <= 32; m <<= 1) {
#pragma unroll
        for (int k = 0; k < 8; k++) {
            ssum[k] += __shfl_xor(ssum[k], m);
            ssq[k] += __shfl_xor(ssq[k], m);
        }
    }
    __shared__ float ls[64], lq[64];
    if (t < 64) { ls[t] = 0.f; lq[t] = 0.f; }
    __syncthreads();
    if (ns == 0) {
#pragma unroll
        for (int k = 0; k < 8; k++) {
            atomicAdd(&ls[c * 8 + k], ssum[k]);
            atomicAdd(&lq[c * 8 + k], ssq[k]);
        }
    }
    __syncthreads();
    float* sr = stats + (blockIdx.x & 7) * 128;
    if (t < 64) {
        atomicAdd(&sr[t], ls[t]);
        atomicAdd(&sr[64 + t], lq[t]);
    }
}

// ---------- BN1 + ReLU + (h @ W2) * dinv via MFMA, split-bf16 precision ------
// r13 version (measured ~8 us): W2 split/transposed into LDS per block; MFMA
// B-operands from LDS. (r15 lesson: global B-frags inside the MFMA loop cost
// ~26 us in load->MFMA latency — matrix operands want LDS residency.)
__global__ __launch_bounds__(256) void rG_bnmm(const bf16* outb, const float* stats,
                                               const float* gamma, const float* beta,
                                               const float* W2, const float* dinv,
                                               bf16* y) {
    __shared__ short ahi[64 * 72];
    __shared__ short alo[64 * 72];
    __shared__ short bthi[64 * 72];
    __shared__ short btlo[64 * 72];
    __shared__ float scale[HID], shift[HID], dinvl[HID];
    int t = threadIdx.x;
    int nb = blockIdx.x * 64;
    if (t < HID) {
        float s = 0.f, q = 0.f;
#pragma unroll
        for (int r = 0; r < 8; r++) { s += stats[r * 128 + t]; q += stats[r * 128 + 64 + t]; }
        float mu = s * (1.0f / NN);
        float var = q * (1.0f / NN) - mu * mu;
        float rs = rsqrtf(var + EPS);
        float g = gamma[t];
        scale[t] = rs * g;
        shift[t] = beta[t] - mu * rs * g;
        dinvl[t] = dinv[nb + t];
    }
    // W2 split + transpose into bt[col][k]
    for (int i = t; i < HID * HID; i += 256) {
        int k = i >> 6, j = i & 63;
        float w = W2[i];
        bf16 hi = f2b(w);
        float lo = w - b2f(hi);
        bf16 lo16 = f2b(lo);
        bthi[j * 72 + k] = *(short*)&hi;
        btlo[j * 72 + k] = *(short*)&lo16;
    }
    __syncthreads();
    // A staging: BN + ReLU + split, vectorized (8 bf16 per uint4)
    for (int i = t; i < 512; i += 256) {
        uint4 a = *(const uint4*)(outb + (size_t)nb * HID + i * 8);
        int node = i >> 3, k0 = (i & 7) * 8;
        const unsigned* u = (const unsigned*)&a;
        unsigned hw[4], lw[4];
#pragma unroll
        for (int q = 0; q < 4; q++) {
            int k = k0 + 2 * q;
            float f0 = __uint_as_float(u[q] << 16);
            float f1 = __uint_as_float(u[q] & 0xFFFF0000u);
            float h0 = fmaxf(f0 * scale[k] + shift[k], 0.f);
            float h1 = fmaxf(f1 * scale[k + 1] + shift[k + 1], 0.f);
            bf16 h0h = f2b(h0), h1h = f2b(h1);
            float l0 = h0 - b2f(h0h), l1 = h1 - b2f(h1h);
            unsigned short uh0 = *(unsigned short*)&h0h, uh1 = *(unsigned short*)&h1h;
            hw[q] = (unsigned)uh0 | ((unsigned)uh1 << 16);
            bf16 l0h = f2b(l0), l1h = f2b(l1);
            unsigned short ul0 = *(unsigned short*)&l0h, ul1 = *(unsigned short*)&l1h;
            lw[q] = (unsigned)ul0 | ((unsigned)ul1 << 16);
        }
        *(uint4*)(ahi + node * 72 + k0) = *(uint4*)hw;
        *(uint4*)(alo + node * 72 + k0) = *(uint4*)lw;
    }
    __syncthreads();
    // compute: wave w owns row-strip [w*16, w*16+16), all 4 col-tiles
    int lane = t & 63, w = t >> 6;
    int arow = w * 16 + (lane & 15);
    int kg = (lane >> 4) * 8;               // k sub-offset within 32-chunk
    v8s aH0 = *(v8s*)(ahi + arow * 72 + kg);
    v8s aH1 = *(v8s*)(ahi + arow * 72 + 32 + kg);
    v8s aL0 = *(v8s*)(alo + arow * 72 + kg);
    v8s aL1 = *(v8s*)(alo + arow * 72 + 32 + kg);
    float dvr[4];
#pragma unroll
    for (int r = 0; r < 4; r++) dvr[r] = dinvl[w * 16 + (lane >> 4) * 4 + r];
#pragma unroll
    for (int ct = 0; ct < 4; ct++) {
        int bcol = ct * 16 + (lane & 15);
        v8s bH0 = *(v8s*)(bthi + bcol * 72 + kg);
        v8s bH1 = *(v8s*)(bthi + bcol * 72 + 32 + kg);
        v8s bL0 = *(v8s*)(btlo + bcol * 72 + kg);
        v8s bL1 = *(v8s*)(btlo + bcol * 72 + 32 + kg);
        v4f acc = {0.f, 0.f, 0.f, 0.f};
        acc = __builtin_amdgcn_mfma_f32_16x16x32_bf16(aH0, bH0, acc, 0, 0, 0);
        acc = __builtin_amdgcn_mfma_f32_16x16x32_bf16(aH1, bH1, acc, 0, 0, 0);
        acc = __builtin_amdgcn_mfma_f32_16x16x32_bf16(aH0, bL0, acc, 0, 0, 0);
        acc = __builtin_amdgcn_mfma_f32_16x16x32_bf16(aH1, bL1, acc, 0, 0, 0);
        acc = __builtin_amdgcn_mfma_f32_16x16x32_bf16(aL0, bH0, acc, 0, 0, 0);
        acc = __builtin_amdgcn_mfma_f32_16x16x32_bf16(aL1, bH1, acc, 0, 0, 0);
#pragma unroll
        for (int r = 0; r < 4; r++) {
            int n = nb + w * 16 + (lane >> 4) * 4 + r;
            y[(size_t)n * HID + ct * 16 + (lane & 15)] = f2b(acc[r] * dvr[r]);
        }
    }
}

// ---------- BN2 + ReLU + mean pool + concat + fused MLP heads (unchanged) ----
__global__ __launch_bounds__(256) void rG_pool(const bf16* outb, const float* stats,
                                               const float* gamma, const float* beta,
                                               const int* graph_cnt, const float* gf,
                                               const float* Wo1, const float* bo1,
                                               const float* Wo2, const float* bo2,
                                               const float* Wb1, const float* bb1,
                                               const float* Wb2, const float* bb2,
                                               int* err, float* out) {
    __shared__ float scale[HID], shift[HID];
    __shared__ float red[4][64];
    __shared__ float cl[80];
    __shared__ int pcnt[1024];
    __shared__ int rsum[256];
    __shared__ int g0s;
    int t = threadIdx.x;
    int g = blockIdx.x;
    if (t < HID) {
        float s = 0.f, q = 0.f;
#pragma unroll
        for (int r = 0; r < 8; r++) { s += stats[r * 128 + t]; q += stats[r * 128 + 64 + t]; }
        float mu = s * (1.0f / NN);
        float var = q * (1.0f / NN) - mu * mu;
        float rs = rsqrtf(var + EPS);
        float ga = gamma[t];
        scale[t] = rs * ga;
        shift[t] = beta[t] - mu * rs * ga;
    }
    // masked reduce: g0 = sum(graph_cnt[0..g-1])
    int part = 0;
    for (int i = t; i < NG; i += 256) {
        int v = graph_cnt[i];
        pcnt[i] = v;
        if (i < g) part += v;
    }
    rsum[t] = part;
    __syncthreads();
    for (int off = 128; off > 0; off >>= 1) {
        if (t < off) rsum[t] += rsum[t + off];
        __syncthreads();
    }
    if (t == 0) g0s = rsum[0];
    __syncthreads();
    int g0 = g0s, g1 = g0 + pcnt[g];
    int c = t & 7, r = t >> 3;
    float acc[8];
#pragma unroll
    for (int k = 0; k < 8; k++) acc[k] = 0.f;
    for (int n = g0 + r; n < g1; n += 32) {
        uint4 a = *(const uint4*)(outb + (size_t)n * HID + c * 8);
        const unsigned* u = (const unsigned*)&a;
#pragma unroll
        for (int q = 0; q < 4; q++) {
            int k = c * 8 + 2 * q;
            float f0 = __uint_as_float(u[q] << 16);
            float f1 = __uint_as_float(u[q] & 0xFFFF0000u);
            acc[2 * q]     += fmaxf(f0 * scale[k] + shift[k], 0.f);
            acc[2 * q + 1] += fmaxf(f1 * scale[k + 1] + shift[k + 1], 0.f);
        }
    }
#pragma unroll
    for (int m = 8; m <= 32; m <<= 1) {
#pragma unroll
        for (int k = 0; k < 8; k++) acc[k] += __shfl_xor(acc[k], m);
    }
    int lane = t & 63, w = t >> 6;
    if (lane < 8) {
#pragma unroll
        for (int k = 0; k < 8; k++) red[w][lane * 8 + k] = acc[k];
    }
    if (t >= 64 && t < 80) cl[t] = gf[g * GFC + (t - 64)];
    __syncthreads();
    if (t < 64) {
        float tot = red[0][t] + red[1][t] + red[2][t] + red[3][t];
        float cn = (float)(g1 - g0);
        cl[t] = tot / fmaxf(cn, 1.0f);
    }
    __syncthreads();
    if (t < 64) {
        int j = t & 31, br = t >> 5;
        const float* W1 = br ? Wb1 : Wo1;
        const float* B1 = br ? bb1 : bo1;
        const float* W2h = br ? Wb2 : Wo2;
        const float* B2 = br ? bb2 : bo2;
        float z = B1[j];
#pragma unroll
        for (int k = 0; k < 80; k++) z += cl[k] * W1[k * 32 + j];
        float v = fmaxf(z, 0.f) * W2h[j];
#pragma unroll
        for (int m = 1; m < 32; m <<= 1) v += __shfl_xor(v, m);
        if (j == 0) {
            int code = atomicAdd(err, 0);
            out[br * NG + g] = code ? (float)code : (v + B2[0]);
        }
    }
}

extern "C" void kernel_launch(void* const* d_in, const int* in_sizes, int n_in,
                              void* d_out, int out_size, void* d_ws, size_t ws_size,
                              hipStream_t stream) {
    const int expect[20] = {
        NN * FIN, 2 * NE, NN, NG * GFC,
        FIN * HID, HID, HID, HID,
        HID * HID, HID, HID, HID,
        (HID + GFC) * (HID / 2), HID / 2, HID / 2, 1,
        (HID + GFC) * (HID / 2), HID / 2, HID / 2, 1
    };
    if (n_in != 20) {
        rG_code<<<8, 256, 0, stream>>>(9000.0f + (float)n_in, (float*)d_out);
        return;
    }
    for (int i = 0; i < 20; i++) {
        if (in_sizes[i] != expect[i]) {
            rG_code<<<8, 256, 0, stream>>>(8000.0f + 50.0f * (float)i, (float*)d_out);
            return;
        }
    }
    if (out_size != 2048) {
        rG_code<<<8, 256, 0, stream>>>(9900.0f, (float*)d_out);
        return;
    }

    const float* x    = (const float*)d_in[0];
    const int*   ei   = (const int*)d_in[1];
    const int*   bat  = (const int*)d_in[2];
    const float* gf   = (const float*)d_in[3];
    const float* W1   = (const float*)d_in[4];
    const float* b1   = (const float*)d_in[5];
    const float* g1   = (const float*)d_in[6];
    const float* be1  = (const float*)d_in[7];
    const float* W2   = (const float*)d_in[8];
    const float* b2   = (const float*)d_in[9];
    const float* g2   = (const float*)d_in[10];
    const float* be2  = (const float*)d_in[11];
    const float* Wo1  = (const float*)d_in[12];
    const float* bo1  = (const float*)d_in[13];
    const float* Wo2  = (const float*)d_in[14];
    const float* bo2  = (const float*)d_in[15];
    const float* Wb1  = (const float*)d_in[16];
    const float* bb1  = (const float*)d_in[17];
    const float* Wb2  = (const float*)d_in[18];
    const float* bb2  = (const float*)d_in[19];

    // ---- workspace layout: ALL gather-target buffers 256-B aligned ----------
    // ints before ybuf = 3648 + NN(deg) + NN(dinv) + (NN+64)(row_ptr)
    //                  + (NBK*PBCAP+64)(col_src) = 3,247,808
    //                  -> 12,991,232 B, %256==0 ✓ (r9 lesson)
    char* base = (char*)d_ws;
    int*   err        = (int*)base;                        // 64, zeroed
    int*   graph_cnt  = err + 64;                          // NG, zeroed
    float* stats      = (float*)(graph_cnt + NG);          // 2048, zeroed
    int*   bin_cnt    = (int*)(stats + 2048);              // NBK, zeroed
    int*   deg        = bin_cnt + NBK;                     // NN, zeroed
    char*  zero_end   = (char*)(deg + NN);
    float* dinv       = (float*)(deg + NN);                // NN
    int*   row_ptr    = (int*)(dinv + NN);                 // NN+64
    int*   col_src    = row_ptr + NN + 64;                 // NBK*PBCAP + 64 slack
    bf16*  ybuf       = (bf16*)(col_src + NBK * PBCAP + 64);  // (NN+2)*HID rows:
                                                           // row NN = zeros, NN+1 = pad
    bf16*  outb       = ybuf + (size_t)(NN + 2) * HID;
    char*  wend       = (char*)(outb + (size_t)NN * HID);
    unsigned* bin     = (unsigned*)outb;                   // 9.83 MB < outb 16.78 MB;
                                                           // consumed by rG_sortxw before
                                                           // agg1 first writes outb
    size_t need = (size_t)(wend - base);
    if (ws_size < need) {
        rG_code<<<8, 256, 0, stream>>>(4000.0f + 4.0f * (float)(ws_size >> 20), (float*)d_out);
        return;
    }

    hipMemsetAsync(d_ws, 0, (size_t)(zero_end - base), stream);

    rG_bin<<<NBK, 1024, 0, stream>>>(ei, bat, bin, bin_cnt, deg, graph_cnt, err);
    rG_sortxw<<<NBK, 1024, 0, stream>>>(bin, bin_cnt, deg, x, W1,
                                        row_ptr, dinv, col_src, ybuf, err);
    rG_agg<<<2048, 256, 0, stream>>>(row_ptr, deg, col_src, dinv, b1, ybuf, outb, stats);
    rG_bnmm<<<NN / 64, 256, 0, stream>>>(outb, stats, g1, be1, W2, dinv, ybuf);
    rG_agg<<<2048, 256, 0, stream>>>(row_ptr, deg, col_src, dinv, b2, ybuf, outb, stats + 1024);
    rG_pool<<<NG, 256, 0, stream>>>(outb, stats + 1024, g2, be2, graph_cnt, gf,
                                    Wo1, bo1, Wo2, bo2, Wb1, bb1, Wb2, bb2,
                                    err, (float*)d_out);
}

// Round 17
// 254.003 us; speedup vs baseline: 1.2907x; 1.2907x over previous
//
#include <hip/hip_runtime.h>
#include <hip/hip_bf16.h>

#define NN 131072
#define NE 2097152
#define FIN 32
#define HID 64
#define GFC 16
#define NG 1024
#define EPS 1e-5f
#define NBK 512      // buckets (dst>>8), 256 nodes each
#define BCAP 4800    // per-bucket bin capacity (mean 4096, +11 sigma)
#define PBCAP 5568   // padded bucket capacity: BCAP + 256*3 (pad-to-4)

typedef __hip_bfloat16 bf16;
typedef __attribute__((ext_vector_type(8))) short v8s;   // 8 bf16 = 4 VGPRs
typedef __attribute__((ext_vector_type(4))) float v4f;   // MFMA accumulator

__device__ __forceinline__ bf16 f2b(float v) { return __float2bfloat16(v); }
__device__ __forceinline__ float b2f(bf16 v) { return __bfloat162float(v); }
__device__ __forceinline__ void rG_err(int* err, int code) { atomicCAS(err, 0, code); }

// pack two f32 -> 2x bf16 in one u32
__device__ __forceinline__ unsigned rG_pk(float a, float b) {
    bf16 h0 = f2b(a), h1 = f2b(b);
    unsigned short u0 = *(unsigned short*)&h0;
    unsigned short u1 = *(unsigned short*)&h1;
    return (unsigned)u0 | ((unsigned)u1 << 16);
}

// accumulate 8 bf16 (as uint4) into acc[8]
__device__ __forceinline__ void rG_add8(float* acc, uint4 a) {
    const unsigned* u = (const unsigned*)&a;
#pragma unroll
    for (int q = 0; q < 4; q++) {
        acc[2 * q]     += __uint_as_float(u[q] << 16);
        acc[2 * q + 1] += __uint_as_float(u[q] & 0xFFFF0000u);
    }
}

// ---------- broadcast diagnostic code (f32 output) ----------
__global__ void rG_code(float code, float* out) {
    int i = blockIdx.x * blockDim.x + threadIdx.x;
    if (i < 2048) out[i] = code;
}

// ---------- bin edges into 512 coarse buckets (dst>>8), + fused batch hist ---
// (r16 lesson: NO per-node global atomics here — 2M device-scope scattered
// atomics serialize at the LLC (non-coherent per-XCD L2s) and cost ~70 us.
// Per-node counting happens in rG_sortxw's LDS pass instead.)
__global__ __launch_bounds__(1024) void rG_bin(const int* ei, const int* batch,
                                               unsigned* bin, int* bin_cnt,
                                               int* graph_cnt, int* err) {
    __shared__ unsigned lsort[4096];
    __shared__ unsigned short bof[4096];
    __shared__ int h[NBK];
    __shared__ int h2[NBK];
    __shared__ int lbase[NBK];
    __shared__ int gbase[NBK];
    int t = threadIdx.x;
    // fused batch histogram: 256 sorted nodes per block (waves 0-3)
    if (t < 256) {
        int lane = t & 63;
        int n = blockIdx.x * 256 + t;
        int bg = batch[n];
        if ((unsigned)bg >= NG) { rG_err(err, 3100); bg = 0; }
        int bgp = __shfl_up(bg, 1);
        bool head = (lane == 0) || (bgp != bg);
        int bgn = __shfl_down(bg, 1);
        bool last = (lane == 63) || (bgn != bg);
        unsigned long long hm = __ballot(head);
        if (last) {
            unsigned long long below =
                (lane == 63) ? hm : (hm & ((1ULL << (lane + 1)) - 1ULL));
            int start = 63 - __clzll(below);
            atomicAdd(&graph_cnt[bg], lane - start + 1);
        }
    }
    if (t < NBK) { h[t] = 0; h2[t] = 0; }
    __syncthreads();
    // 4096 edges/block = 1 int4 per thread per array
    const int4* si4 = (const int4*)ei;
    const int4* di4 = (const int4*)(ei + NE);
    int e4 = blockIdx.x * 1024 + t;
    int4 s4 = si4[e4];
    int4 d4 = di4[e4];
    int sv[4] = {s4.x, s4.y, s4.z, s4.w};
    int dv[4] = {d4.x, d4.y, d4.z, d4.w};
    unsigned vals[4];
    unsigned short bks[4];
#pragma unroll
    for (int q = 0; q < 4; q++) {
        int s = sv[q], d = dv[q];
        if ((unsigned)s >= NN || (unsigned)d >= NN) { rG_err(err, 3000); s = 0; d = 0; }
        int b = d >> 8;
        vals[q] = ((unsigned)(d & 255) << 17) | (unsigned)s;
        bks[q] = (unsigned short)b;
        atomicAdd(&h[b], 1);
    }
    __syncthreads();
    // inclusive scan of h (512 entries, first 512 threads)
    if (t < NBK) lbase[t] = h[t];
    __syncthreads();
    for (int off = 1; off < NBK; off <<= 1) {
        int v = 0;
        if (t < NBK && t >= off) v = lbase[t - off];
        __syncthreads();
        if (t < NBK) lbase[t] += v;
        __syncthreads();
    }
    if (t < NBK) {
        gbase[t] = atomicAdd(&bin_cnt[t], h[t]);
        lbase[t] -= h[t];   // exclusive
    }
    __syncthreads();
    // scatter into LDS, sorted by bucket
#pragma unroll
    for (int q = 0; q < 4; q++) {
        int b = bks[q];
        int r = atomicAdd(&h2[b], 1);
        int pos = lbase[b] + r;
        lsort[pos] = vals[q];
        bof[pos] = (unsigned short)b;
    }
    __syncthreads();
    // coalesced copy-out: consecutive i within a run -> consecutive global addrs
    for (int i = t; i < 4096; i += 1024) {
        int b = bof[i];
        int p = gbase[b] + (i - lbase[b]);
        if (p >= BCAP) { rG_err(err, 3800); continue; }
        bin[b * BCAP + p] = lsort[i];
    }
}

// ---------- per-bucket sort (512 blocks x 1024 thr, 256 locals, pad-to-4) ----
// + block 0 NE validation + fused xw1 (lout reused for W1/x staging)
__global__ __launch_bounds__(1024) void rG_sortxw(const unsigned* bin, const int* bin_cnt,
                                                  const float* x, const float* W1,
                                                  int* row_ptr, int* degp, float* dinv,
                                                  int* col_src, bf16* y, int* err) {
    __shared__ int cnt[256];
    __shared__ int sA[256];
    __shared__ int sB[256];
    __shared__ float dinvl[256];
    __shared__ int lout[6272];   // 25 KB: max(PBCAP=5568, ws 2048 + xs 4224)
    int t = threadIdx.x;
    int b = blockIdx.x;
    if (t < 256) cnt[t] = 0;
    __syncthreads();
    int m = bin_cnt[b];
    if (m > BCAP) m = BCAP;
    // pass 1: count dst-locals (coalesced global read, L2-hot)
    for (int j = t; j < m; j += 1024) {
        int dl = bin[b * BCAP + j] >> 17;
        atomicAdd(&cnt[dl], 1);
    }
    __syncthreads();
    // inclusive scan of 4-PADDED counts, 256 entries
    if (t < 256) sA[t] = (cnt[t] + 3) & ~3;
    __syncthreads();
    int* src = sA;
    int* dst = sB;
    for (int off = 1; off < 256; off <<= 1) {
        if (t < 256) dst[t] = src[t] + ((t >= off) ? src[t - off] : 0);
        __syncthreads();
        int* tmp = src; src = dst; dst = tmp;
    }
    // src = inclusive scan of cnt4; dst free for local bases.
    // Pad slots [basl+c, basl+c4) written with sentinel directly (disjoint from
    // scatter targets [basl, basl+c)).
    int gb = b * PBCAP;
    if (t < 256) {
        int c = cnt[t];
        int c4 = (c + 3) & ~3;
        int basl = src[t] - c4;             // local base within bucket
        dst[t] = basl;
        row_ptr[b * 256 + t] = gb + basl;
        degp[b * 256 + t] = c4;
        float dv = rsqrtf((float)c + 1.0f);
        dinv[b * 256 + t] = dv;
        dinvl[t] = dv;
        for (int k = c; k < c4; k++) lout[basl + k] = NN;
    }
    __syncthreads();
    int tot = src[255];                     // total padded edges this bucket
    if (t < 256) cnt[t] = 0;                // reset cursors
    __syncthreads();
    // pass 2: scatter into LDS
    for (int j = t; j < m; j += 1024) {
        unsigned v = bin[b * BCAP + j];
        int dl = v >> 17;
        int r = atomicAdd(&cnt[dl], 1);
        lout[dst[dl] + r] = (int)(v & 0x1FFFFu);
    }
    __syncthreads();
    // fully coalesced write-out
    for (int i = t; i < tot; i += 1024) col_src[gb + i] = lout[i];
    __syncthreads();
    // ---- block 0: validate total edge count ----
    if (b == 0) {
        if (t < 256) sA[t] = bin_cnt[t] + bin_cnt[t + 256];
        __syncthreads();
        for (int off = 128; off > 0; off >>= 1) {
            if (t < off) sA[t] += sA[t + off];
            __syncthreads();
        }
        if (t == 0 && sA[0] != NE) rG_err(err, 2000);
    }
    // ---- fused xw1 for nodes b*256 .. +255 (lout memory now dead) ----
    float* ws = (float*)lout;               // FIN*HID = 2048 f32 (8 KB)
    float* xs = ws + FIN * HID;             // 128*(FIN+1) = 4224 f32 (16.9 KB)
    for (int i = t; i < FIN * HID; i += 1024) ws[i] = W1[i];
    if (b == 0 && t < HID) y[(size_t)NN * HID + t] = f2b(0.f);  // zero row
    for (int ch = 0; ch < 2; ch++) {
        __syncthreads();                    // xs reuse + (first iter) ws ready
        int nb0 = b * 256 + ch * 128;
        {
            // 128 nodes x 32 f32 = 1024 float4: one per thread
            float4 f4 = ((const float4*)x)[(size_t)nb0 * 8 + t];
            int nd = t >> 3, k4 = (t & 7) * 4;
            float* xp = xs + nd * (FIN + 1) + k4;
            xp[0] = f4.x; xp[1] = f4.y; xp[2] = f4.z; xp[3] = f4.w;
        }
        __syncthreads();
        int node = t >> 3, fg = t & 7;
        float acc[8];
#pragma unroll
        for (int j = 0; j < 8; j++) acc[j] = 0.f;
        for (int k = 0; k < FIN; k++) {
            float xv = xs[node * (FIN + 1) + k];
#pragma unroll
            for (int j = 0; j < 8; j++) acc[j] += xv * ws[k * HID + fg * 8 + j];
        }
        float dv = dinvl[ch * 128 + node];
        unsigned o[4];
#pragma unroll
        for (int q = 0; q < 4; q++) o[q] = rG_pk(acc[2 * q] * dv, acc[2 * q + 1] * dv);
        *(uint4*)(y + (size_t)(nb0 + node) * HID + fg * 8) = *(uint4*)o;
    }
}

// ---------- CSR aggregation: DUAL-STREAM, 16 nodes/wave, pad-to-4 rows -------
__global__ __launch_bounds__(256) void rG_agg(const int* row_ptr, const int* degp,
                                              const int* col_src,
                                              const float* dinv, const float* bias,
                                              const bf16* y, bf16* outb, float* stats) {
    int t = threadIdx.x;
    int lane = t & 63, wave = t >> 6;
    int ns = lane >> 3;
    int c = lane & 7;
    float bl[8];
#pragma unroll
    for (int k = 0; k < 8; k++) bl[k] = bias[c * 8 + k];
    float ssum[8], ssq[8];
#pragma unroll
    for (int k = 0; k < 8; k++) { ssum[k] = 0.f; ssq[k] = 0.f; }
    int gw = blockIdx.x * 4 + wave;
    int nw = gridDim.x * 4;
    for (int nb = gw * 16; nb < NN; nb += nw * 16) {
        int nA = nb + ns, nB = nb + 8 + ns;
        int eA = row_ptr[nA], eA1 = eA + degp[nA];
        int eB = row_ptr[nB], eB1 = eB + degp[nB];
        float accA[8], accB[8];
#pragma unroll
        for (int k = 0; k < 8; k++) { accA[k] = 0.f; accB[k] = 0.f; }
        uint4 svA = *(const uint4*)(y + (size_t)nA * HID + c * 8);
        uint4 svB = *(const uint4*)(y + (size_t)nB * HID + c * 8);
        uint4 iA0 = {0, 0, 0, 0}, iA1 = iA0, iB0 = iA0, iB1 = iA0;
        if (eA < eA1) {
            iA0 = *(const uint4*)(col_src + eA);
            iA1 = *(const uint4*)(col_src + eA + 4);
        }
        if (eB < eB1) {
            iB0 = *(const uint4*)(col_src + eB);
            iB1 = *(const uint4*)(col_src + eB + 4);
        }
        rG_add8(accA, svA);
        rG_add8(accB, svB);
        while (eA + 8 <= eA1 || eB + 8 <= eB1) {
            bool pA = eA + 8 <= eA1, pB = eB + 8 <= eB1;
            uint4 fA0 = iA0, fA1 = iA1, fB0 = iB0, fB1 = iB1;
            if (pA && eA + 8 < eA1) {
                fA0 = *(const uint4*)(col_src + eA + 8);
                fA1 = *(const uint4*)(col_src + eA + 12);
            }
            if (pB && eB + 8 < eB1) {
                fB0 = *(const uint4*)(col_src + eB + 8);
                fB1 = *(const uint4*)(col_src + eB + 12);
            }
            uint4 gA[8], gB[8];
            if (pA) {
                int ix[8] = {(int)iA0.x, (int)iA0.y, (int)iA0.z, (int)iA0.w,
                             (int)iA1.x, (int)iA1.y, (int)iA1.z, (int)iA1.w};
#pragma unroll
                for (int i = 0; i < 8; i++)
                    gA[i] = *(const uint4*)(y + (size_t)ix[i] * HID + c * 8);
            }
            if (pB) {
                int ix[8] = {(int)iB0.x, (int)iB0.y, (int)iB0.z, (int)iB0.w,
                             (int)iB1.x, (int)iB1.y, (int)iB1.z, (int)iB1.w};
#pragma unroll
                for (int i = 0; i < 8; i++)
                    gB[i] = *(const uint4*)(y + (size_t)ix[i] * HID + c * 8);
            }
            if (pA) {
#pragma unroll
                for (int i = 0; i < 8; i++) rG_add8(accA, gA[i]);
                eA += 8; iA0 = fA0; iA1 = fA1;
            }
            if (pB) {
#pragma unroll
                for (int i = 0; i < 8; i++) rG_add8(accB, gB[i]);
                eB += 8; iB0 = fB0; iB1 = fB1;
            }
        }
        if (eA < eA1) {                           // 4-tail (indices in iA0)
            int ix[4] = {(int)iA0.x, (int)iA0.y, (int)iA0.z, (int)iA0.w};
            uint4 g[4];
#pragma unroll
            for (int i = 0; i < 4; i++)
                g[i] = *(const uint4*)(y + (size_t)ix[i] * HID + c * 8);
#pragma unroll
            for (int i = 0; i < 4; i++) rG_add8(accA, g[i]);
        }
        if (eB < eB1) {                           // 4-tail (indices in iB0)
            int ix[4] = {(int)iB0.x, (int)iB0.y, (int)iB0.z, (int)iB0.w};
            uint4 g[4];
#pragma unroll
            for (int i = 0; i < 4; i++)
                g[i] = *(const uint4*)(y + (size_t)ix[i] * HID + c * 8);
#pragma unroll
            for (int i = 0; i < 4; i++) rG_add8(accB, g[i]);
        }
        {
            float dv = dinv[nA];
            unsigned ob[4];
#pragma unroll
            for (int q = 0; q < 4; q++) {
                float o0 = accA[2 * q] * dv + bl[2 * q];
                float o1 = accA[2 * q + 1] * dv + bl[2 * q + 1];
                ssum[2 * q] += o0; ssq[2 * q] += o0 * o0;
                ssum[2 * q + 1] += o1; ssq[2 * q + 1] += o1 * o1;
                ob[q] = rG_pk(o0, o1);
            }
            *(uint4*)(outb + (size_t)nA * HID + c * 8) = *(uint4*)ob;
        }
        {
            float dv = dinv[nB];
            unsigned ob[4];
#pragma unroll
            for (int q = 0; q < 4; q++) {
                float o0 = accB[2 * q] * dv + bl[2 * q];
                float o1 = accB[2 * q + 1] * dv + bl[2 * q + 1];
                ssum[2 * q] += o0; ssq[2 * q] += o0 * o0;
                ssum[2 * q + 1] += o1; ssq[2 * q + 1] += o1 * o1;
                ob[q] = rG_pk(o0, o1);
            }
            *(uint4*)(outb + (size_t)nB * HID + c * 8) = *(uint4*)ob;
        }
    }
#pragma unroll
    for (int m = 8; m <= 32; m <<= 1) {
#pragma unroll
        for (int k = 0; k < 8; k++) {
            ssum[k] += __shfl_xor(ssum[k], m);
            ssq[k] += __shfl_xor(ssq[k], m);
        }
    }
    __shared__ float ls[64], lq[64];
    if (t < 64) { ls[t] = 0.f; lq[t] = 0.f; }
    __syncthreads();
    if (ns == 0) {
#pragma unroll
        for (int k = 0; k < 8; k++) {
            atomicAdd(&ls[c * 8 + k], ssum[k]);
            atomicAdd(&lq[c * 8 + k], ssq[k]);
        }
    }
    __syncthreads();
    float* sr = stats + (blockIdx.x & 7) * 128;
    if (t < 64) {
        atomicAdd(&sr[t], ls[t]);
        atomicAdd(&sr[64 + t], lq[t]);
    }
}

// ---------- BN1 + ReLU + (h @ W2) * dinv via MFMA, split-bf16 precision ------
// A = relu(bn(outb)) [64x64], B = W2 [64x64]. Split x = hi + lo (both bf16);
// C = Ahi*Bhi + Ahi*Blo + Alo*Bhi (lo*lo ~2^-18 dropped) => f32-level accuracy.
// W2 split/transposed into LDS per block (r15 lesson: global B-frags inside
// the MFMA loop cost ~26 us in load->MFMA latency — operands want LDS).
__global__ __launch_bounds__(256) void rG_bnmm(const bf16* outb, const float* stats,
                                               const float* gamma, const float* beta,
                                               const float* W2, const float* dinv,
                                               bf16* y) {
    __shared__ short ahi[64 * 72];
    __shared__ short alo[64 * 72];
    __shared__ short bthi[64 * 72];
    __shared__ short btlo[64 * 72];
    __shared__ float scale[HID], shift[HID], dinvl[HID];
    int t = threadIdx.x;
    int nb = blockIdx.x * 64;
    if (t < HID) {
        float s = 0.f, q = 0.f;
#pragma unroll
        for (int r = 0; r < 8; r++) { s += stats[r * 128 + t]; q += stats[r * 128 + 64 + t]; }
        float mu = s * (1.0f / NN);
        float var = q * (1.0f / NN) - mu * mu;
        float rs = rsqrtf(var + EPS);
        float g = gamma[t];
        scale[t] = rs * g;
        shift[t] = beta[t] - mu * rs * g;
        dinvl[t] = dinv[nb + t];
    }
    // W2 split + transpose into bt[col][k] (one-time 4096-elem staging)
    for (int i = t; i < HID * HID; i += 256) {
        int k = i >> 6, j = i & 63;
        float w = W2[i];
        bf16 hi = f2b(w);
        float lo = w - b2f(hi);
        bf16 lo16 = f2b(lo);
        bthi[j * 72 + k] = *(short*)&hi;
        btlo[j * 72 + k] = *(short*)&lo16;
    }
    __syncthreads();
    // A staging: BN + ReLU + split, vectorized (8 bf16 per uint4)
    for (int i = t; i < 512; i += 256) {
        uint4 a = *(const uint4*)(outb + (size_t)nb * HID + i * 8);
        int node = i >> 3, k0 = (i & 7) * 8;
        const unsigned* u = (const unsigned*)&a;
        unsigned hw[4], lw[4];
#pragma unroll
        for (int q = 0; q < 4; q++) {
            int k = k0 + 2 * q;
            float f0 = __uint_as_float(u[q] << 16);
            float f1 = __uint_as_float(u[q] & 0xFFFF0000u);
            float h0 = fmaxf(f0 * scale[k] + shift[k], 0.f);
            float h1 = fmaxf(f1 * scale[k + 1] + shift[k + 1], 0.f);
            bf16 h0h = f2b(h0), h1h = f2b(h1);
            float l0 = h0 - b2f(h0h), l1 = h1 - b2f(h1h);
            unsigned short uh0 = *(unsigned short*)&h0h, uh1 = *(unsigned short*)&h1h;
            hw[q] = (unsigned)uh0 | ((unsigned)uh1 << 16);
            bf16 l0h = f2b(l0), l1h = f2b(l1);
            unsigned short ul0 = *(unsigned short*)&l0h, ul1 = *(unsigned short*)&l1h;
            lw[q] = (unsigned)ul0 | ((unsigned)ul1 << 16);
        }
        *(uint4*)(ahi + node * 72 + k0) = *(uint4*)hw;
        *(uint4*)(alo + node * 72 + k0) = *(uint4*)lw;
    }
    __syncthreads();
    // compute: wave w owns row-strip [w*16, w*16+16), all 4 col-tiles
    int lane = t & 63, w = t >> 6;
    int arow = w * 16 + (lane & 15);
    int kg = (lane >> 4) * 8;               // k sub-offset within 32-chunk
    v8s aH0 = *(v8s*)(ahi + arow * 72 + kg);
    v8s aH1 = *(v8s*)(ahi + arow * 72 + 32 + kg);
    v8s aL0 = *(v8s*)(alo + arow * 72 + kg);
    v8s aL1 = *(v8s*)(alo + arow * 72 + 32 + kg);
    float dvr[4];
#pragma unroll
    for (int r = 0; r < 4; r++) dvr[r] = dinvl[w * 16 + (lane >> 4) * 4 + r];
#pragma unroll
    for (int ct = 0; ct < 4; ct++) {
        int bcol = ct * 16 + (lane & 15);
        v8s bH0 = *(v8s*)(bthi + bcol * 72 + kg);
        v8s bH1 = *(v8s*)(bthi + bcol * 72 + 32 + kg);
        v8s bL0 = *(v8s*)(btlo + bcol * 72 + kg);
        v8s bL1 = *(v8s*)(btlo + bcol * 72 + 32 + kg);
        v4f acc = {0.f, 0.f, 0.f, 0.f};
        acc = __builtin_amdgcn_mfma_f32_16x16x32_bf16(aH0, bH0, acc, 0, 0, 0);
        acc = __builtin_amdgcn_mfma_f32_16x16x32_bf16(aH1, bH1, acc, 0, 0, 0);
        acc = __builtin_amdgcn_mfma_f32_16x16x32_bf16(aH0, bL0, acc, 0, 0, 0);
        acc = __builtin_amdgcn_mfma_f32_16x16x32_bf16(aH1, bL1, acc, 0, 0, 0);
        acc = __builtin_amdgcn_mfma_f32_16x16x32_bf16(aL0, bH0, acc, 0, 0, 0);
        acc = __builtin_amdgcn_mfma_f32_16x16x32_bf16(aL1, bH1, acc, 0, 0, 0);
#pragma unroll
        for (int r = 0; r < 4; r++) {
            int n = nb + w * 16 + (lane >> 4) * 4 + r;
            y[(size_t)n * HID + ct * 16 + (lane & 15)] = f2b(acc[r] * dvr[r]);
        }
    }
}

// ---------- BN2 + ReLU + mean pool + concat + fused MLP heads ----------------
__global__ __launch_bounds__(256) void rG_pool(const bf16* outb, const float* stats,
                                               const float* gamma, const float* beta,
                                               const int* graph_cnt, const float* gf,
                                               const float* Wo1, const float* bo1,
                                               const float* Wo2, const float* bo2,
                                               const float* Wb1, const float* bb1,
                                               const float* Wb2, const float* bb2,
                                               int* err, float* out) {
    __shared__ float scale[HID], shift[HID];
    __shared__ float red[4][64];
    __shared__ float cl[80];
    __shared__ int pcnt[1024];
    __shared__ int rsum[256];
    __shared__ int g0s;
    int t = threadIdx.x;
    int g = blockIdx.x;
    if (t < HID) {
        float s = 0.f, q = 0.f;
#pragma unroll
        for (int r = 0; r < 8; r++) { s += stats[r * 128 + t]; q += stats[r * 128 + 64 + t]; }
        float mu = s * (1.0f / NN);
        float var = q * (1.0f / NN) - mu * mu;
        float rs = rsqrtf(var + EPS);
        float ga = gamma[t];
        scale[t] = rs * ga;
        shift[t] = beta[t] - mu * rs * ga;
    }
    // masked reduce: g0 = sum(graph_cnt[0..g-1])
    int part = 0;
    for (int i = t; i < NG; i += 256) {
        int v = graph_cnt[i];
        pcnt[i] = v;
        if (i < g) part += v;
    }
    rsum[t] = part;
    __syncthreads();
    for (int off = 128; off > 0; off >>= 1) {
        if (t < off) rsum[t] += rsum[t + off];
        __syncthreads();
    }
    if (t == 0) g0s = rsum[0];
    __syncthreads();
    int g0 = g0s, g1 = g0 + pcnt[g];
    int c = t & 7, r = t >> 3;
    float acc[8];
#pragma unroll
    for (int k = 0; k < 8; k++) acc[k] = 0.f;
    for (int n = g0 + r; n < g1; n += 32) {
        uint4 a = *(const uint4*)(outb + (size_t)n * HID + c * 8);
        const unsigned* u = (const unsigned*)&a;
#pragma unroll
        for (int q = 0; q < 4; q++) {
            int k = c * 8 + 2 * q;
            float f0 = __uint_as_float(u[q] << 16);
            float f1 = __uint_as_float(u[q] & 0xFFFF0000u);
            acc[2 * q]     += fmaxf(f0 * scale[k] + shift[k], 0.f);
            acc[2 * q + 1] += fmaxf(f1 * scale[k + 1] + shift[k + 1], 0.f);
        }
    }
#pragma unroll
    for (int m = 8; m <= 32; m <<= 1) {
#pragma unroll
        for (int k = 0; k < 8; k++) acc[k] += __shfl_xor(acc[k], m);
    }
    int lane = t & 63, w = t >> 6;
    if (lane < 8) {
#pragma unroll
        for (int k = 0; k < 8; k++) red[w][lane * 8 + k] = acc[k];
    }
    if (t >= 64 && t < 80) cl[t] = gf[g * GFC + (t - 64)];
    __syncthreads();
    if (t < 64) {
        float tot = red[0][t] + red[1][t] + red[2][t] + red[3][t];
        float cn = (float)(g1 - g0);
        cl[t] = tot / fmaxf(cn, 1.0f);
    }
    __syncthreads();
    if (t < 64) {
        int j = t & 31, br = t >> 5;
        const float* W1 = br ? Wb1 : Wo1;
        const float* B1 = br ? bb1 : bo1;
        const float* W2h = br ? Wb2 : Wo2;
        const float* B2 = br ? bb2 : bo2;
        float z = B1[j];
#pragma unroll
        for (int k = 0; k < 80; k++) z += cl[k] * W1[k * 32 + j];
        float v = fmaxf(z, 0.f) * W2h[j];
#pragma unroll
        for (int m = 1; m < 32; m <<= 1) v += __shfl_xor(v, m);
        if (j == 0) {
            int code = atomicAdd(err, 0);
            out[br * NG + g] = code ? (float)code : (v + B2[0]);
        }
    }
}

extern "C" void kernel_launch(void* const* d_in, const int* in_sizes, int n_in,
                              void* d_out, int out_size, void* d_ws, size_t ws_size,
                              hipStream_t stream) {
    const int expect[20] = {
        NN * FIN, 2 * NE, NN, NG * GFC,
        FIN * HID, HID, HID, HID,
        HID * HID, HID, HID, HID,
        (HID + GFC) * (HID / 2), HID / 2, HID / 2, 1,
        (HID + GFC) * (HID / 2), HID / 2, HID / 2, 1
    };
    if (n_in != 20) {
        rG_code<<<8, 256, 0, stream>>>(9000.0f + (float)n_in, (float*)d_out);
        return;
    }
    for (int i = 0; i < 20; i++) {
        if (in_sizes[i] != expect[i]) {
            rG_code<<<8, 256, 0, stream>>>(8000.0f + 50.0f * (float)i, (float*)d_out);
            return;
        }
    }
    if (out_size != 2048) {
        rG_code<<<8, 256, 0, stream>>>(9900.0f, (float*)d_out);
        return;
    }

    const float* x    = (const float*)d_in[0];
    const int*   ei   = (const int*)d_in[1];
    const int*   bat  = (const int*)d_in[2];
    const float* gf   = (const float*)d_in[3];
    const float* W1   = (const float*)d_in[4];
    const float* b1   = (const float*)d_in[5];
    const float* g1   = (const float*)d_in[6];
    const float* be1  = (const float*)d_in[7];
    const float* W2   = (const float*)d_in[8];
    const float* b2   = (const float*)d_in[9];
    const float* g2   = (const float*)d_in[10];
    const float* be2  = (const float*)d_in[11];
    const float* Wo1  = (const float*)d_in[12];
    const float* bo1  = (const float*)d_in[13];
    const float* Wo2  = (const float*)d_in[14];
    const float* bo2  = (const float*)d_in[15];
    const float* Wb1  = (const float*)d_in[16];
    const float* bb1  = (const float*)d_in[17];
    const float* Wb2  = (const float*)d_in[18];
    const float* bb2  = (const float*)d_in[19];

    // ---- workspace layout: ALL gather-target buffers 256-B aligned ----------
    // (r9 lesson: misaligned ybuf doubled FETCH. Verified: ints before ybuf =
    //  3648 + NN + (NN+64) + NN + (NBK*PBCAP+64) = 3,247,808 -> 12,991,232 B,
    //  %256==0 ✓; ybuf rows are 128 B so outb stays aligned.)
    char* base = (char*)d_ws;
    int*   err        = (int*)base;                        // 64, zeroed
    int*   graph_cnt  = err + 64;                          // NG, zeroed
    float* stats      = (float*)(graph_cnt + NG);          // 2048, zeroed
    int*   bin_cnt    = (int*)(stats + 2048);              // NBK, zeroed
    char*  zero_end   = (char*)(bin_cnt + NBK);
    float* dinv       = (float*)(bin_cnt + NBK);           // NN
    int*   row_ptr    = (int*)(dinv + NN);                 // NN+64
    int*   degp       = row_ptr + NN + 64;                 // NN (4-padded degree)
    int*   col_src    = degp + NN;                         // NBK*PBCAP + 64 slack
    bf16*  ybuf       = (bf16*)(col_src + NBK * PBCAP + 64);  // (NN+2)*HID rows:
                                                           // row NN = zeros, NN+1 = pad
    bf16*  outb       = ybuf + (size_t)(NN + 2) * HID;
    char*  wend       = (char*)(outb + (size_t)NN * HID);
    unsigned* bin     = (unsigned*)outb;                   // 9.83 MB < outb 16.78 MB;
                                                           // consumed by rG_sortxw before
                                                           // agg1 first writes outb
    size_t need = (size_t)(wend - base);
    if (ws_size < need) {
        rG_code<<<8, 256, 0, stream>>>(4000.0f + 4.0f * (float)(ws_size >> 20), (float*)d_out);
        return;
    }

    hipMemsetAsync(d_ws, 0, (size_t)(zero_end - base), stream);

    rG_bin<<<NBK, 1024, 0, stream>>>(ei, bat, bin, bin_cnt, graph_cnt, err);
    rG_sortxw<<<NBK, 1024, 0, stream>>>(bin, bin_cnt, x, W1, row_ptr, degp, dinv,
                                        col_src, ybuf, err);
    rG_agg<<<2048, 256, 0, stream>>>(row_ptr, degp, col_src, dinv, b1, ybuf, outb, stats);
    rG_bnmm<<<NN / 64, 256, 0, stream>>>(outb, stats, g1, be1, W2, dinv, ybuf);
    rG_agg<<<2048, 256, 0, stream>>>(row_ptr, degp, col_src, dinv, b2, ybuf, outb, stats + 1024);
    rG_pool<<<NG, 256, 0, stream>>>(outb, stats + 1024, g2, be2, graph_cnt, gf,
                                    Wo1, bo1, Wo2, bo2, Wb1, bb1, Wb2, bb2,
                                    err, (float*)d_out);
}

// Round 18
// 250.631 us; speedup vs baseline: 1.3081x; 1.0135x over previous
//
#include <hip/hip_runtime.h>
#include <hip/hip_bf16.h>

#define NN 131072
#define NE 2097152
#define FIN 32
#define HID 64
#define GFC 16
#define NG 1024
#define EPS 1e-5f
#define NBK 512      // buckets (dst>>8), 256 nodes each
#define BCAP 4800    // per-bucket bin capacity (mean 4096, +11 sigma)
#define PBCAP 5568   // padded bucket capacity: BCAP + 256*3 (pad-to-4)

typedef __hip_bfloat16 bf16;
typedef __attribute__((ext_vector_type(8))) short v8s;   // 8 bf16 = 4 VGPRs
typedef __attribute__((ext_vector_type(4))) float v4f;   // MFMA accumulator

__device__ __forceinline__ bf16 f2b(float v) { return __float2bfloat16(v); }
__device__ __forceinline__ float b2f(bf16 v) { return __bfloat162float(v); }
__device__ __forceinline__ void rG_err(int* err, int code) { atomicCAS(err, 0, code); }

// pack two f32 -> 2x bf16 in one u32
__device__ __forceinline__ unsigned rG_pk(float a, float b) {
    bf16 h0 = f2b(a), h1 = f2b(b);
    unsigned short u0 = *(unsigned short*)&h0;
    unsigned short u1 = *(unsigned short*)&h1;
    return (unsigned)u0 | ((unsigned)u1 << 16);
}

// accumulate 8 bf16 (as uint4) into acc[8]
__device__ __forceinline__ void rG_add8(float* acc, uint4 a) {
    const unsigned* u = (const unsigned*)&a;
#pragma unroll
    for (int q = 0; q < 4; q++) {
        acc[2 * q]     += __uint_as_float(u[q] << 16);
        acc[2 * q + 1] += __uint_as_float(u[q] & 0xFFFF0000u);
    }
}

// wave-local inclusive scan (64 lanes)
__device__ __forceinline__ int rG_wscan(int v, int ln) {
#pragma unroll
    for (int off = 1; off < 64; off <<= 1) {
        int u = __shfl_up(v, off);
        if (ln >= off) v += u;
    }
    return v;
}

// ---------- broadcast diagnostic code (f32 output) ----------
__global__ void rG_code(float code, float* out) {
    int i = blockIdx.x * blockDim.x + threadIdx.x;
    if (i < 2048) out[i] = code;
}

// ---------- bin edges into 512 coarse buckets (dst>>8), + fused batch hist ---
// (r16 lesson: no per-node global atomics. This round: 512-entry scan via
// hierarchical shuffle scan — 4 barriers instead of 19.)
__global__ __launch_bounds__(1024) void rG_bin(const int* ei, const int* batch,
                                               unsigned* bin, int* bin_cnt,
                                               int* graph_cnt, int* err) {
    __shared__ unsigned lsort[4096];
    __shared__ unsigned short bof[4096];
    __shared__ int h[NBK];
    __shared__ int h2[NBK];
    __shared__ int lbase[NBK];
    __shared__ int gbase[NBK];
    __shared__ int wtot[8];
    int t = threadIdx.x;
    int wv = t >> 6, ln = t & 63;
    // fused batch histogram: 256 sorted nodes per block (waves 0-3)
    if (t < 256) {
        int n = blockIdx.x * 256 + t;
        int bg = batch[n];
        if ((unsigned)bg >= NG) { rG_err(err, 3100); bg = 0; }
        int bgp = __shfl_up(bg, 1);
        bool head = (ln == 0) || (bgp != bg);
        int bgn = __shfl_down(bg, 1);
        bool last = (ln == 63) || (bgn != bg);
        unsigned long long hm = __ballot(head);
        if (last) {
            unsigned long long below =
                (ln == 63) ? hm : (hm & ((1ULL << (ln + 1)) - 1ULL));
            int start = 63 - __clzll(below);
            atomicAdd(&graph_cnt[bg], ln - start + 1);
        }
    }
    if (t < NBK) { h[t] = 0; h2[t] = 0; }
    __syncthreads();
    // 4096 edges/block = 1 int4 per thread per array
    const int4* si4 = (const int4*)ei;
    const int4* di4 = (const int4*)(ei + NE);
    int e4 = blockIdx.x * 1024 + t;
    int4 s4 = si4[e4];
    int4 d4 = di4[e4];
    int sv[4] = {s4.x, s4.y, s4.z, s4.w};
    int dv[4] = {d4.x, d4.y, d4.z, d4.w};
    unsigned vals[4];
    unsigned short bks[4];
#pragma unroll
    for (int q = 0; q < 4; q++) {
        int s = sv[q], d = dv[q];
        if ((unsigned)s >= NN || (unsigned)d >= NN) { rG_err(err, 3000); s = 0; d = 0; }
        int b = d >> 8;
        vals[q] = ((unsigned)(d & 255) << 17) | (unsigned)s;
        bks[q] = (unsigned short)b;
        atomicAdd(&h[b], 1);
    }
    __syncthreads();
    // hierarchical shuffle scan of h (512 entries = waves 0..7)
    int hv = 0;
    if (t < NBK) {
        hv = h[t];
        int vs = rG_wscan(hv, ln);
        lbase[t] = vs;                      // wave-local inclusive
        if (ln == 63) wtot[wv] = vs;        // per-wave totals
    }
    __syncthreads();
    if (t < 8) {
        int v = wtot[t];
        int vs = v;
#pragma unroll
        for (int off = 1; off < 8; off <<= 1) {
            int u = __shfl_up(vs, off);
            if (t >= off) vs += u;
        }
        wtot[t] = vs - v;                   // exclusive wave offset
    }
    __syncthreads();
    if (t < NBK) {
        int inc = lbase[t] + wtot[wv];      // global inclusive
        gbase[t] = atomicAdd(&bin_cnt[t], hv);
        lbase[t] = inc - hv;                // exclusive
    }
    __syncthreads();
    // scatter into LDS, sorted by bucket
#pragma unroll
    for (int q = 0; q < 4; q++) {
        int b = bks[q];
        int r = atomicAdd(&h2[b], 1);
        int pos = lbase[b] + r;
        lsort[pos] = vals[q];
        bof[pos] = (unsigned short)b;
    }
    __syncthreads();
    // coalesced copy-out: consecutive i within a run -> consecutive global addrs
    for (int i = t; i < 4096; i += 1024) {
        int b = bof[i];
        int p = gbase[b] + (i - lbase[b]);
        if (p >= BCAP) { rG_err(err, 3800); continue; }
        bin[b * BCAP + p] = lsort[i];
    }
}

// ---------- per-bucket sort (512 blocks x 1024 thr, 256 locals, pad-to-4) ----
// 256-entry scan via hierarchical shuffle scan (4 barriers vs 17).
// + block 0 NE validation + fused xw1 (lout reused for W1/x staging)
__global__ __launch_bounds__(1024) void rG_sortxw(const unsigned* bin, const int* bin_cnt,
                                                  const float* x, const float* W1,
                                                  int* row_ptr, int* degp, float* dinv,
                                                  int* col_src, bf16* y, int* err) {
    __shared__ int cnt[256];
    __shared__ int sA[256];
    __shared__ int sB[256];
    __shared__ int wtot[4];
    __shared__ float dinvl[256];
    __shared__ int lout[6272];   // 25 KB: max(PBCAP=5568, ws 2048 + xs 4224)
    int t = threadIdx.x;
    int b = blockIdx.x;
    int wv = t >> 6, ln = t & 63;
    if (t < 256) cnt[t] = 0;
    __syncthreads();
    int m = bin_cnt[b];
    if (m > BCAP) m = BCAP;
    // pass 1: count dst-locals (coalesced global read, L2-hot)
    for (int j = t; j < m; j += 1024) {
        int dl = bin[b * BCAP + j] >> 17;
        atomicAdd(&cnt[dl], 1);
    }
    __syncthreads();
    // hierarchical shuffle scan of 4-padded counts (256 entries = waves 0..3)
    int c = 0, c4 = 0;
    if (t < 256) {
        c = cnt[t];
        c4 = (c + 3) & ~3;
        int vs = rG_wscan(c4, ln);
        sA[t] = vs;
        if (ln == 63) wtot[wv] = vs;
    }
    __syncthreads();
    if (t < 4) {
        int v = wtot[t];
        int vs = v;
#pragma unroll
        for (int off = 1; off < 4; off <<= 1) {
            int u = __shfl_up(vs, off);
            if (t >= off) vs += u;
        }
        wtot[t] = vs - v;                   // exclusive wave offset
    }
    __syncthreads();
    int gb = b * PBCAP;
    if (t < 256) {
        int inc = sA[t] + wtot[wv];         // global inclusive
        sA[t] = inc;
        int basl = inc - c4;                // local base within bucket
        sB[t] = basl;
        row_ptr[b * 256 + t] = gb + basl;
        degp[b * 256 + t] = c4;
        float dvv = rsqrtf((float)c + 1.0f);
        dinv[b * 256 + t] = dvv;
        dinvl[t] = dvv;
        for (int k = c; k < c4; k++) lout[basl + k] = NN;   // sentinel pads
    }
    __syncthreads();
    int tot = sA[255];                      // total padded edges this bucket
    if (t < 256) cnt[t] = 0;                // reset cursors
    __syncthreads();
    // pass 2: scatter into LDS
    for (int j = t; j < m; j += 1024) {
        unsigned v = bin[b * BCAP + j];
        int dl = v >> 17;
        int r = atomicAdd(&cnt[dl], 1);
        lout[sB[dl] + r] = (int)(v & 0x1FFFFu);
    }
    __syncthreads();
    // fully coalesced write-out
    for (int i = t; i < tot; i += 1024) col_src[gb + i] = lout[i];
    __syncthreads();
    // ---- block 0: validate total edge count ----
    if (b == 0) {
        if (t < 256) sA[t] = bin_cnt[t] + bin_cnt[t + 256];
        __syncthreads();
        for (int off = 128; off > 0; off >>= 1) {
            if (t < off) sA[t] += sA[t + off];
            __syncthreads();
        }
        if (t == 0 && sA[0] != NE) rG_err(err, 2000);
    }
    // ---- fused xw1 for nodes b*256 .. +255 (lout memory now dead) ----
    float* ws = (float*)lout;               // FIN*HID = 2048 f32 (8 KB)
    float* xs = ws + FIN * HID;             // 128*(FIN+1) = 4224 f32 (16.9 KB)
    for (int i = t; i < FIN * HID; i += 1024) ws[i] = W1[i];
    if (b == 0 && t < HID) y[(size_t)NN * HID + t] = f2b(0.f);  // zero row
    for (int ch = 0; ch < 2; ch++) {
        __syncthreads();                    // xs reuse + (first iter) ws ready
        int nb0 = b * 256 + ch * 128;
        {
            // 128 nodes x 32 f32 = 1024 float4: one per thread
            float4 f4 = ((const float4*)x)[(size_t)nb0 * 8 + t];
            int nd = t >> 3, k4 = (t & 7) * 4;
            float* xp = xs + nd * (FIN + 1) + k4;
            xp[0] = f4.x; xp[1] = f4.y; xp[2] = f4.z; xp[3] = f4.w;
        }
        __syncthreads();
        int node = t >> 3, fg = t & 7;
        float acc[8];
#pragma unroll
        for (int j = 0; j < 8; j++) acc[j] = 0.f;
        for (int k = 0; k < FIN; k++) {
            float xv = xs[node * (FIN + 1) + k];
#pragma unroll
            for (int j = 0; j < 8; j++) acc[j] += xv * ws[k * HID + fg * 8 + j];
        }
        float dvv = dinvl[ch * 128 + node];
        unsigned o[4];
#pragma unroll
        for (int q = 0; q < 4; q++) o[q] = rG_pk(acc[2 * q] * dvv, acc[2 * q + 1] * dvv);
        *(uint4*)(y + (size_t)(nb0 + node) * HID + fg * 8) = *(uint4*)o;
    }
}

// ---------- CSR aggregation: DUAL-STREAM, 16 nodes/wave, pad-to-4 rows -------
// (byte-identical to r17)
__global__ __launch_bounds__(256) void rG_agg(const int* row_ptr, const int* degp,
                                              const int* col_src,
                                              const float* dinv, const float* bias,
                                              const bf16* y, bf16* outb, float* stats) {
    int t = threadIdx.x;
    int lane = t & 63, wave = t >> 6;
    int ns = lane >> 3;
    int c = lane & 7;
    float bl[8];
#pragma unroll
    for (int k = 0; k < 8; k++) bl[k] = bias[c * 8 + k];
    float ssum[8], ssq[8];
#pragma unroll
    for (int k = 0; k < 8; k++) { ssum[k] = 0.f; ssq[k] = 0.f; }
    int gw = blockIdx.x * 4 + wave;
    int nw = gridDim.x * 4;
    for (int nb = gw * 16; nb < NN; nb += nw * 16) {
        int nA = nb + ns, nB = nb + 8 + ns;
        int eA = row_ptr[nA], eA1 = eA + degp[nA];
        int eB = row_ptr[nB], eB1 = eB + degp[nB];
        float accA[8], accB[8];
#pragma unroll
        for (int k = 0; k < 8; k++) { accA[k] = 0.f; accB[k] = 0.f; }
        uint4 svA = *(const uint4*)(y + (size_t)nA * HID + c * 8);
        uint4 svB = *(const uint4*)(y + (size_t)nB * HID + c * 8);
        uint4 iA0 = {0, 0, 0, 0}, iA1 = iA0, iB0 = iA0, iB1 = iA0;
        if (eA < eA1) {
            iA0 = *(const uint4*)(col_src + eA);
            iA1 = *(const uint4*)(col_src + eA + 4);
        }
        if (eB < eB1) {
            iB0 = *(const uint4*)(col_src + eB);
            iB1 = *(const uint4*)(col_src + eB + 4);
        }
        rG_add8(accA, svA);
        rG_add8(accB, svB);
        while (eA + 8 <= eA1 || eB + 8 <= eB1) {
            bool pA = eA + 8 <= eA1, pB = eB + 8 <= eB1;
            uint4 fA0 = iA0, fA1 = iA1, fB0 = iB0, fB1 = iB1;
            if (pA && eA + 8 < eA1) {
                fA0 = *(const uint4*)(col_src + eA + 8);
                fA1 = *(const uint4*)(col_src + eA + 12);
            }
            if (pB && eB + 8 < eB1) {
                fB0 = *(const uint4*)(col_src + eB + 8);
                fB1 = *(const uint4*)(col_src + eB + 12);
            }
            uint4 gA[8], gB[8];
            if (pA) {
                int ix[8] = {(int)iA0.x, (int)iA0.y, (int)iA0.z, (int)iA0.w,
                             (int)iA1.x, (int)iA1.y, (int)iA1.z, (int)iA1.w};
#pragma unroll
                for (int i = 0; i < 8; i++)
                    gA[i] = *(const uint4*)(y + (size_t)ix[i] * HID + c * 8);
            }
            if (pB) {
                int ix[8] = {(int)iB0.x, (int)iB0.y, (int)iB0.z, (int)iB0.w,
                             (int)iB1.x, (int)iB1.y, (int)iB1.z, (int)iB1.w};
#pragma unroll
                for (int i = 0; i < 8; i++)
                    gB[i] = *(const uint4*)(y + (size_t)ix[i] * HID + c * 8);
            }
            if (pA) {
#pragma unroll
                for (int i = 0; i < 8; i++) rG_add8(accA, gA[i]);
                eA += 8; iA0 = fA0; iA1 = fA1;
            }
            if (pB) {
#pragma unroll
                for (int i = 0; i < 8; i++) rG_add8(accB, gB[i]);
                eB += 8; iB0 = fB0; iB1 = fB1;
            }
        }
        if (eA < eA1) {                           // 4-tail (indices in iA0)
            int ix[4] = {(int)iA0.x, (int)iA0.y, (int)iA0.z, (int)iA0.w};
            uint4 g[4];
#pragma unroll
            for (int i = 0; i < 4; i++)
                g[i] = *(const uint4*)(y + (size_t)ix[i] * HID + c * 8);
#pragma unroll
            for (int i = 0; i < 4; i++) rG_add8(accA, g[i]);
        }
        if (eB < eB1) {                           // 4-tail (indices in iB0)
            int ix[4] = {(int)iB0.x, (int)iB0.y, (int)iB0.z, (int)iB0.w};
            uint4 g[4];
#pragma unroll
            for (int i = 0; i < 4; i++)
                g[i] = *(const uint4*)(y + (size_t)ix[i] * HID + c * 8);
#pragma unroll
            for (int i = 0; i < 4; i++) rG_add8(accB, g[i]);
        }
        {
            float dv = dinv[nA];
            unsigned ob[4];
#pragma unroll
            for (int q = 0; q < 4; q++) {
                float o0 = accA[2 * q] * dv + bl[2 * q];
                float o1 = accA[2 * q + 1] * dv + bl[2 * q + 1];
                ssum[2 * q] += o0; ssq[2 * q] += o0 * o0;
                ssum[2 * q + 1] += o1; ssq[2 * q + 1] += o1 * o1;
                ob[q] = rG_pk(o0, o1);
            }
            *(uint4*)(outb + (size_t)nA * HID + c * 8) = *(uint4*)ob;
        }
        {
            float dv = dinv[nB];
            unsigned ob[4];
#pragma unroll
            for (int q = 0; q < 4; q++) {
                float o0 = accB[2 * q] * dv + bl[2 * q];
                float o1 = accB[2 * q + 1] * dv + bl[2 * q + 1];
                ssum[2 * q] += o0; ssq[2 * q] += o0 * o0;
                ssum[2 * q + 1] += o1; ssq[2 * q + 1] += o1 * o1;
                ob[q] = rG_pk(o0, o1);
            }
            *(uint4*)(outb + (size_t)nB * HID + c * 8) = *(uint4*)ob;
        }
    }
#pragma unroll
    for (int m = 8; m <= 32; m <<= 1) {
#pragma unroll
        for (int k = 0; k < 8; k++) {
            ssum[k] += __shfl_xor(ssum[k], m);
            ssq[k] += __shfl_xor(ssq[k], m);
        }
    }
    __shared__ float ls[64], lq[64];
    if (t < 64) { ls[t] = 0.f; lq[t] = 0.f; }
    __syncthreads();
    if (ns == 0) {
#pragma unroll
        for (int k = 0; k < 8; k++) {
            atomicAdd(&ls[c * 8 + k], ssum[k]);
            atomicAdd(&lq[c * 8 + k], ssq[k]);
        }
    }
    __syncthreads();
    float* sr = stats + (blockIdx.x & 7) * 128;
    if (t < 64) {
        atomicAdd(&sr[t], ls[t]);
        atomicAdd(&sr[64 + t], lq[t]);
    }
}

// ---------- BN1 + ReLU + (h @ W2) * dinv via MFMA, split-bf16 precision ------
// (byte-identical to r17: W2 split/transposed into LDS per block)
__global__ __launch_bounds__(256) void rG_bnmm(const bf16* outb, const float* stats,
                                               const float* gamma, const float* beta,
                                               const float* W2, const float* dinv,
                                               bf16* y) {
    __shared__ short ahi[64 * 72];
    __shared__ short alo[64 * 72];
    __shared__ short bthi[64 * 72];
    __shared__ short btlo[64 * 72];
    __shared__ float scale[HID], shift[HID], dinvl[HID];
    int t = threadIdx.x;
    int nb = blockIdx.x * 64;
    if (t < HID) {
        float s = 0.f, q = 0.f;
#pragma unroll
        for (int r = 0; r < 8; r++) { s += stats[r * 128 + t]; q += stats[r * 128 + 64 + t]; }
        float mu = s * (1.0f / NN);
        float var = q * (1.0f / NN) - mu * mu;
        float rs = rsqrtf(var + EPS);
        float g = gamma[t];
        scale[t] = rs * g;
        shift[t] = beta[t] - mu * rs * g;
        dinvl[t] = dinv[nb + t];
    }
    // W2 split + transpose into bt[col][k] (one-time 4096-elem staging)
    for (int i = t; i < HID * HID; i += 256) {
        int k = i >> 6, j = i & 63;
        float w = W2[i];
        bf16 hi = f2b(w);
        float lo = w - b2f(hi);
        bf16 lo16 = f2b(lo);
        bthi[j * 72 + k] = *(short*)&hi;
        btlo[j * 72 + k] = *(short*)&lo16;
    }
    __syncthreads();
    // A staging: BN + ReLU + split, vectorized (8 bf16 per uint4)
    for (int i = t; i < 512; i += 256) {
        uint4 a = *(const uint4*)(outb + (size_t)nb * HID + i * 8);
        int node = i >> 3, k0 = (i & 7) * 8;
        const unsigned* u = (const unsigned*)&a;
        unsigned hw[4], lw[4];
#pragma unroll
        for (int q = 0; q < 4; q++) {
            int k = k0 + 2 * q;
            float f0 = __uint_as_float(u[q] << 16);
            float f1 = __uint_as_float(u[q] & 0xFFFF0000u);
            float h0 = fmaxf(f0 * scale[k] + shift[k], 0.f);
            float h1 = fmaxf(f1 * scale[k + 1] + shift[k + 1], 0.f);
            bf16 h0h = f2b(h0), h1h = f2b(h1);
            float l0 = h0 - b2f(h0h), l1 = h1 - b2f(h1h);
            unsigned short uh0 = *(unsigned short*)&h0h, uh1 = *(unsigned short*)&h1h;
            hw[q] = (unsigned)uh0 | ((unsigned)uh1 << 16);
            bf16 l0h = f2b(l0), l1h = f2b(l1);
            unsigned short ul0 = *(unsigned short*)&l0h, ul1 = *(unsigned short*)&l1h;
            lw[q] = (unsigned)ul0 | ((unsigned)ul1 << 16);
        }
        *(uint4*)(ahi + node * 72 + k0) = *(uint4*)hw;
        *(uint4*)(alo + node * 72 + k0) = *(uint4*)lw;
    }
    __syncthreads();
    // compute: wave w owns row-strip [w*16, w*16+16), all 4 col-tiles
    int lane = t & 63, w = t >> 6;
    int arow = w * 16 + (lane & 15);
    int kg = (lane >> 4) * 8;               // k sub-offset within 32-chunk
    v8s aH0 = *(v8s*)(ahi + arow * 72 + kg);
    v8s aH1 = *(v8s*)(ahi + arow * 72 + 32 + kg);
    v8s aL0 = *(v8s*)(alo + arow * 72 + kg);
    v8s aL1 = *(v8s*)(alo + arow * 72 + 32 + kg);
    float dvr[4];
#pragma unroll
    for (int r = 0; r < 4; r++) dvr[r] = dinvl[w * 16 + (lane >> 4) * 4 + r];
#pragma unroll
    for (int ct = 0; ct < 4; ct++) {
        int bcol = ct * 16 + (lane & 15);
        v8s bH0 = *(v8s*)(bthi + bcol * 72 + kg);
        v8s bH1 = *(v8s*)(bthi + bcol * 72 + 32 + kg);
        v8s bL0 = *(v8s*)(btlo + bcol * 72 + kg);
        v8s bL1 = *(v8s*)(btlo + bcol * 72 + 32 + kg);
        v4f acc = {0.f, 0.f, 0.f, 0.f};
        acc = __builtin_amdgcn_mfma_f32_16x16x32_bf16(aH0, bH0, acc, 0, 0, 0);
        acc = __builtin_amdgcn_mfma_f32_16x16x32_bf16(aH1, bH1, acc, 0, 0, 0);
        acc = __builtin_amdgcn_mfma_f32_16x16x32_bf16(aH0, bL0, acc, 0, 0, 0);
        acc = __builtin_amdgcn_mfma_f32_16x16x32_bf16(aH1, bL1, acc, 0, 0, 0);
        acc = __builtin_amdgcn_mfma_f32_16x16x32_bf16(aL0, bH0, acc, 0, 0, 0);
        acc = __builtin_amdgcn_mfma_f32_16x16x32_bf16(aL1, bH1, acc, 0, 0, 0);
#pragma unroll
        for (int r = 0; r < 4; r++) {
            int n = nb + w * 16 + (lane >> 4) * 4 + r;
            y[(size_t)n * HID + ct * 16 + (lane & 15)] = f2b(acc[r] * dvr[r]);
        }
    }
}

// ---------- BN2 + ReLU + mean pool + concat + fused MLP heads (unchanged) ----
__global__ __launch_bounds__(256) void rG_pool(const bf16* outb, const float* stats,
                                               const float* gamma, const float* beta,
                                               const int* graph_cnt, const float* gf,
                                               const float* Wo1, const float* bo1,
                                               const float* Wo2, const float* bo2,
                                               const float* Wb1, const float* bb1,
                                               const float* Wb2, const float* bb2,
                                               int* err, float* out) {
    __shared__ float scale[HID], shift[HID];
    __shared__ float red[4][64];
    __shared__ float cl[80];
    __shared__ int pcnt[1024];
    __shared__ int rsum[256];
    __shared__ int g0s;
    int t = threadIdx.x;
    int g = blockIdx.x;
    if (t < HID) {
        float s = 0.f, q = 0.f;
#pragma unroll
        for (int r = 0; r < 8; r++) { s += stats[r * 128 + t]; q += stats[r * 128 + 64 + t]; }
        float mu = s * (1.0f / NN);
        float var = q * (1.0f / NN) - mu * mu;
        float rs = rsqrtf(var + EPS);
        float ga = gamma[t];
        scale[t] = rs * ga;
        shift[t] = beta[t] - mu * rs * ga;
    }
    // masked reduce: g0 = sum(graph_cnt[0..g-1])
    int part = 0;
    for (int i = t; i < NG; i += 256) {
        int v = graph_cnt[i];
        pcnt[i] = v;
        if (i < g) part += v;
    }
    rsum[t] = part;
    __syncthreads();
    for (int off = 128; off > 0; off >>= 1) {
        if (t < off) rsum[t] += rsum[t + off];
        __syncthreads();
    }
    if (t == 0) g0s = rsum[0];
    __syncthreads();
    int g0 = g0s, g1 = g0 + pcnt[g];
    int c = t & 7, r = t >> 3;
    float acc[8];
#pragma unroll
    for (int k = 0; k < 8; k++) acc[k] = 0.f;
    for (int n = g0 + r; n < g1; n += 32) {
        uint4 a = *(const uint4*)(outb + (size_t)n * HID + c * 8);
        const unsigned* u = (const unsigned*)&a;
#pragma unroll
        for (int q = 0; q < 4; q++) {
            int k = c * 8 + 2 * q;
            float f0 = __uint_as_float(u[q] << 16);
            float f1 = __uint_as_float(u[q] & 0xFFFF0000u);
            acc[2 * q]     += fmaxf(f0 * scale[k] + shift[k], 0.f);
            acc[2 * q + 1] += fmaxf(f1 * scale[k + 1] + shift[k + 1], 0.f);
        }
    }
#pragma unroll
    for (int m = 8; m <= 32; m <<= 1) {
#pragma unroll
        for (int k = 0; k < 8; k++) acc[k] += __shfl_xor(acc[k], m);
    }
    int lane = t & 63, w = t >> 6;
    if (lane < 8) {
#pragma unroll
        for (int k = 0; k < 8; k++) red[w][lane * 8 + k] = acc[k];
    }
    if (t >= 64 && t < 80) cl[t] = gf[g * GFC + (t - 64)];
    __syncthreads();
    if (t < 64) {
        float tot = red[0][t] + red[1][t] + red[2][t] + red[3][t];
        float cn = (float)(g1 - g0);
        cl[t] = tot / fmaxf(cn, 1.0f);
    }
    __syncthreads();
    if (t < 64) {
        int j = t & 31, br = t >> 5;
        const float* W1 = br ? Wb1 : Wo1;
        const float* B1 = br ? bb1 : bo1;
        const float* W2h = br ? Wb2 : Wo2;
        const float* B2 = br ? bb2 : bo2;
        float z = B1[j];
#pragma unroll
        for (int k = 0; k < 80; k++) z += cl[k] * W1[k * 32 + j];
        float v = fmaxf(z, 0.f) * W2h[j];
#pragma unroll
        for (int m = 1; m < 32; m <<= 1) v += __shfl_xor(v, m);
        if (j == 0) {
            int code = atomicAdd(err, 0);
            out[br * NG + g] = code ? (float)code : (v + B2[0]);
        }
    }
}

extern "C" void kernel_launch(void* const* d_in, const int* in_sizes, int n_in,
                              void* d_out, int out_size, void* d_ws, size_t ws_size,
                              hipStream_t stream) {
    const int expect[20] = {
        NN * FIN, 2 * NE, NN, NG * GFC,
        FIN * HID, HID, HID, HID,
        HID * HID, HID, HID, HID,
        (HID + GFC) * (HID / 2), HID / 2, HID / 2, 1,
        (HID + GFC) * (HID / 2), HID / 2, HID / 2, 1
    };
    if (n_in != 20) {
        rG_code<<<8, 256, 0, stream>>>(9000.0f + (float)n_in, (float*)d_out);
        return;
    }
    for (int i = 0; i < 20; i++) {
        if (in_sizes[i] != expect[i]) {
            rG_code<<<8, 256, 0, stream>>>(8000.0f + 50.0f * (float)i, (float*)d_out);
            return;
        }
    }
    if (out_size != 2048) {
        rG_code<<<8, 256, 0, stream>>>(9900.0f, (float*)d_out);
        return;
    }

    const float* x    = (const float*)d_in[0];
    const int*   ei   = (const int*)d_in[1];
    const int*   bat  = (const int*)d_in[2];
    const float* gf   = (const float*)d_in[3];
    const float* W1   = (const float*)d_in[4];
    const float* b1   = (const float*)d_in[5];
    const float* g1   = (const float*)d_in[6];
    const float* be1  = (const float*)d_in[7];
    const float* W2   = (const float*)d_in[8];
    const float* b2   = (const float*)d_in[9];
    const float* g2   = (const float*)d_in[10];
    const float* be2  = (const float*)d_in[11];
    const float* Wo1  = (const float*)d_in[12];
    const float* bo1  = (const float*)d_in[13];
    const float* Wo2  = (const float*)d_in[14];
    const float* bo2  = (const float*)d_in[15];
    const float* Wb1  = (const float*)d_in[16];
    const float* bb1  = (const float*)d_in[17];
    const float* Wb2  = (const float*)d_in[18];
    const float* bb2  = (const float*)d_in[19];

    // ---- workspace layout: ALL gather-target buffers 256-B aligned ----------
    // (r9 lesson: misaligned ybuf doubled FETCH. Verified: ints before ybuf =
    //  3648 + NN + (NN+64) + NN + (NBK*PBCAP+64) = 3,247,808 -> 12,991,232 B,
    //  %256==0 ✓; ybuf rows are 128 B so outb stays aligned.)
    char* base = (char*)d_ws;
    int*   err        = (int*)base;                        // 64, zeroed
    int*   graph_cnt  = err + 64;                          // NG, zeroed
    float* stats      = (float*)(graph_cnt + NG);          // 2048, zeroed
    int*   bin_cnt    = (int*)(stats + 2048);              // NBK, zeroed
    char*  zero_end   = (char*)(bin_cnt + NBK);
    float* dinv       = (float*)(bin_cnt + NBK);           // NN
    int*   row_ptr    = (int*)(dinv + NN);                 // NN+64
    int*   degp       = row_ptr + NN + 64;                 // NN (4-padded degree)
    int*   col_src    = degp + NN;                         // NBK*PBCAP + 64 slack
    bf16*  ybuf       = (bf16*)(col_src + NBK * PBCAP + 64);  // (NN+2)*HID rows:
                                                           // row NN = zeros, NN+1 = pad
    bf16*  outb       = ybuf + (size_t)(NN + 2) * HID;
    char*  wend       = (char*)(outb + (size_t)NN * HID);
    unsigned* bin     = (unsigned*)outb;                   // 9.83 MB < outb 16.78 MB;
                                                           // consumed by rG_sortxw before
                                                           // agg1 first writes outb
    size_t need = (size_t)(wend - base);
    if (ws_size < need) {
        rG_code<<<8, 256, 0, stream>>>(4000.0f + 4.0f * (float)(ws_size >> 20), (float*)d_out);
        return;
    }

    hipMemsetAsync(d_ws, 0, (size_t)(zero_end - base), stream);

    rG_bin<<<NBK, 1024, 0, stream>>>(ei, bat, bin, bin_cnt, graph_cnt, err);
    rG_sortxw<<<NBK, 1024, 0, stream>>>(bin, bin_cnt, x, W1, row_ptr, degp, dinv,
                                        col_src, ybuf, err);
    rG_agg<<<2048, 256, 0, stream>>>(row_ptr, degp, col_src, dinv, b1, ybuf, outb, stats);
    rG_bnmm<<<NN / 64, 256, 0, stream>>>(outb, stats, g1, be1, W2, dinv, ybuf);
    rG_agg<<<2048, 256, 0, stream>>>(row_ptr, degp, col_src, dinv, b2, ybuf, outb, stats + 1024);
    rG_pool<<<NG, 256, 0, stream>>>(outb, stats + 1024, g2, be2, graph_cnt, gf,
                                    Wo1, bo1, Wo2, bo2, Wb1, bb1, Wb2, bb2,
                                    err, (float*)d_out);
}